// Round 4
// baseline (109.469 us; speedup 1.0000x reference)
//
#include <hip/hip_runtime.h>

#define MUL 128
#define RPB 4      // rows per block
#define BLOCK 256

__global__ __launch_bounds__(BLOCK) void cg_tp_kernel(
    const float* __restrict__ x1,
    const float* __restrict__ x2,
    const float* __restrict__ wts,
    float* __restrict__ out,
    int N)
{
    constexpr float INV_SQRT3 = 0.57735026918962576451f;
    constexpr float INV_SQRT2 = 0.70710678118654752440f;

    // Per-row: x1=512, w=640, x2=4, out=1408 floats. Total LDS = 4*2564*4 = 41 KB.
    __shared__ float s_x1[RPB][512];
    __shared__ float s_w [RPB][640];
    __shared__ float s_x2[RPB][4];
    __shared__ float s_out[RPB][1408];

    const int tid  = threadIdx.x;
    const int row0 = blockIdx.x * RPB;
    const int nrows = min(RPB, N - row0);

    // ---- Stage inputs: all contiguous float4 loads ----
    {
        const float4* g = (const float4*)(x1 + (size_t)row0 * 512);
        float4* s = (float4*)&s_x1[0][0];
        for (int i = tid; i < nrows * 128; i += BLOCK) s[i] = g[i];
    }
    {
        const float4* g = (const float4*)(wts + (size_t)row0 * 640);
        float4* s = (float4*)&s_w[0][0];
        for (int i = tid; i < nrows * 160; i += BLOCK) s[i] = g[i];
    }
    {
        const float4* g = (const float4*)(x2 + (size_t)row0 * 4);
        float4* s = (float4*)&s_x2[0][0];
        if (tid < nrows) s[tid] = g[tid];
    }
    __syncthreads();

    // ---- Compute: one (row, channel) task per iteration ----
    for (int j = tid; j < nrows * MUL; j += BLOCK) {
        const int r = j >> 7;
        const int u = j & 127;

        float x10 = s_x1[r][u];
        float a0  = s_x1[r][128 + 3 * u + 0];
        float a1  = s_x1[r][128 + 3 * u + 1];
        float a2  = s_x1[r][128 + 3 * u + 2];
        float sc  = s_x2[r][0];
        float b0  = s_x2[r][1];
        float b1  = s_x2[r][2];
        float b2  = s_x2[r][3];
        float w0  = s_w[r][0 * MUL + u];
        float w1  = s_w[r][1 * MUL + u];
        float w2  = s_w[r][2 * MUL + u];
        float w3  = s_w[r][3 * MUL + u];
        float w4  = s_w[r][4 * MUL + u];

        // out0: 0e x 0e -> 0e
        s_out[r][u] = w0 * x10 * sc;

        // out1: 0e x 1o -> 1o
        float w1x = w1 * x10;
        s_out[r][128 + 3 * u + 0] = w1x * b0;
        s_out[r][128 + 3 * u + 1] = w1x * b1;
        s_out[r][128 + 3 * u + 2] = w1x * b2;

        // out2: 1o x 0e -> 1o
        float w2s = w2 * sc;
        s_out[r][512 + 3 * u + 0] = w2s * a0;
        s_out[r][512 + 3 * u + 1] = w2s * a1;
        s_out[r][512 + 3 * u + 2] = w2s * a2;

        // out3: 1o . 1o -> 0e
        float dot = a0 * b0 + a1 * b1 + a2 * b2;
        s_out[r][896 + u] = w3 * dot * INV_SQRT3;

        // out4: 1o x 1o -> 1e (cross product)
        float c0 = a1 * b2 - a2 * b1;
        float c1 = a2 * b0 - a0 * b2;
        float c2 = a0 * b1 - a1 * b0;
        float w4s = w4 * INV_SQRT2;
        s_out[r][1024 + 3 * u + 0] = w4s * c0;
        s_out[r][1024 + 3 * u + 1] = w4s * c1;
        s_out[r][1024 + 3 * u + 2] = w4s * c2;
    }
    __syncthreads();

    // ---- Write out: contiguous float4 stream ----
    {
        float4* g = (float4*)(out + (size_t)row0 * 1408);
        const float4* s = (const float4*)&s_out[0][0];
        for (int i = tid; i < nrows * 352; i += BLOCK) g[i] = s[i];
    }
}

extern "C" void kernel_launch(void* const* d_in, const int* in_sizes, int n_in,
                              void* d_out, int out_size, void* d_ws, size_t ws_size,
                              hipStream_t stream)
{
    const float* x1  = (const float*)d_in[0];
    const float* x2  = (const float*)d_in[1];
    const float* wts = (const float*)d_in[2];
    float* out = (float*)d_out;

    int N = in_sizes[0] / 512;  // x1 is [N, 512]
    int grid = (N + RPB - 1) / RPB;
    cg_tp_kernel<<<grid, BLOCK, 0, stream>>>(x1, x2, wts, out, N);
}

// Round 5
// 107.822 us; speedup vs baseline: 1.0153x; 1.0153x over previous
//
#include <hip/hip_runtime.h>

#define MUL 128
#define BLOCK 256

// 4 channels per thread: 32 threads per row. All global accesses are aligned float4.
__global__ __launch_bounds__(BLOCK) void cg_tp_kernel(
    const float* __restrict__ x1,
    const float* __restrict__ x2,
    const float* __restrict__ wts,
    float* __restrict__ out,
    int N)
{
    constexpr float INV_SQRT3 = 0.57735026918962576451f;
    constexpr float INV_SQRT2 = 0.70710678118654752440f;

    int t = blockIdx.x * blockDim.x + threadIdx.x;
    int total = N * 32;
    if (t >= total) return;

    int row = t >> 5;        // t / 32
    int q   = t & 31;        // channel-quad index; channels u0..u0+3
    int u0  = q * 4;

    const float* x1r  = x1  + (size_t)row * 512;
    const float* x2r  = x2  + (size_t)row * 4;
    const float* wr   = wts + (size_t)row * 640;
    float*       outr = out + (size_t)row * 1408;

    // ---- Loads (all aligned float4) ----
    float4 X0 = *(const float4*)(x1r + u0);             // x1_0 for 4 channels
    const float4* ap = (const float4*)(x1r + 128 + 12 * q);
    float av[12];                                        // x1_1: a[c][j] = av[3c+j]
    *(float4*)&av[0] = ap[0];
    *(float4*)&av[4] = ap[1];
    *(float4*)&av[8] = ap[2];

    float4 X2 = *(const float4*)x2r;                     // s, b0, b1, b2
    float s = X2.x, b0 = X2.y, b1 = X2.z, b2 = X2.w;

    float4 W0 = *(const float4*)(wr + 0 * MUL + u0);
    float4 W1 = *(const float4*)(wr + 1 * MUL + u0);
    float4 W2 = *(const float4*)(wr + 2 * MUL + u0);
    float4 W3 = *(const float4*)(wr + 3 * MUL + u0);
    float4 W4 = *(const float4*)(wr + 4 * MUL + u0);

    float x0v[4] = {X0.x, X0.y, X0.z, X0.w};
    float w0v[4] = {W0.x, W0.y, W0.z, W0.w};
    float w1v[4] = {W1.x, W1.y, W1.z, W1.w};
    float w2v[4] = {W2.x, W2.y, W2.z, W2.w};
    float w3v[4] = {W3.x, W3.y, W3.z, W3.w};
    float w4v[4] = {W4.x, W4.y, W4.z, W4.w};

    // ---- out0: 0e x 0e -> 0e  [0,128) ----
    {
        float o[4];
#pragma unroll
        for (int c = 0; c < 4; ++c) o[c] = w0v[c] * x0v[c] * s;
        *(float4*)(outr + u0) = *(float4*)&o[0];
    }

    // ---- out1: 0e x 1o -> 1o  [128,512) ----
    {
        float o[12];
#pragma unroll
        for (int c = 0; c < 4; ++c) {
            float wx = w1v[c] * x0v[c];
            o[3 * c + 0] = wx * b0;
            o[3 * c + 1] = wx * b1;
            o[3 * c + 2] = wx * b2;
        }
        float4* g = (float4*)(outr + 128 + 12 * q);
        g[0] = *(float4*)&o[0];
        g[1] = *(float4*)&o[4];
        g[2] = *(float4*)&o[8];
    }

    // ---- out2: 1o x 0e -> 1o  [512,896) ----
    {
        float o[12];
#pragma unroll
        for (int c = 0; c < 4; ++c) {
            float ws = w2v[c] * s;
            o[3 * c + 0] = ws * av[3 * c + 0];
            o[3 * c + 1] = ws * av[3 * c + 1];
            o[3 * c + 2] = ws * av[3 * c + 2];
        }
        float4* g = (float4*)(outr + 512 + 12 * q);
        g[0] = *(float4*)&o[0];
        g[1] = *(float4*)&o[4];
        g[2] = *(float4*)&o[8];
    }

    // ---- out3: 1o . 1o -> 0e  [896,1024) ----
    {
        float o[4];
#pragma unroll
        for (int c = 0; c < 4; ++c) {
            float dot = av[3 * c] * b0 + av[3 * c + 1] * b1 + av[3 * c + 2] * b2;
            o[c] = w3v[c] * dot * INV_SQRT3;
        }
        *(float4*)(outr + 896 + u0) = *(float4*)&o[0];
    }

    // ---- out4: 1o x 1o -> 1e (cross)  [1024,1408) ----
    {
        float o[12];
#pragma unroll
        for (int c = 0; c < 4; ++c) {
            float a0 = av[3 * c], a1 = av[3 * c + 1], a2 = av[3 * c + 2];
            float ws = w4v[c] * INV_SQRT2;
            o[3 * c + 0] = ws * (a1 * b2 - a2 * b1);
            o[3 * c + 1] = ws * (a2 * b0 - a0 * b2);
            o[3 * c + 2] = ws * (a0 * b1 - a1 * b0);
        }
        float4* g = (float4*)(outr + 1024 + 12 * q);
        g[0] = *(float4*)&o[0];
        g[1] = *(float4*)&o[4];
        g[2] = *(float4*)&o[8];
    }
}

extern "C" void kernel_launch(void* const* d_in, const int* in_sizes, int n_in,
                              void* d_out, int out_size, void* d_ws, size_t ws_size,
                              hipStream_t stream)
{
    const float* x1  = (const float*)d_in[0];
    const float* x2  = (const float*)d_in[1];
    const float* wts = (const float*)d_in[2];
    float* out = (float*)d_out;

    int N = in_sizes[0] / 512;  // x1 is [N, 512]
    int total = N * 32;         // 4 channels per thread
    int grid = (total + BLOCK - 1) / BLOCK;
    cg_tp_kernel<<<grid, BLOCK, 0, stream>>>(x1, x2, wts, out, N);
}